// Round 8
// baseline (272.689 us; speedup 1.0000x reference)
//
#include <hip/hip_runtime.h>

// ---------- types ----------
typedef __attribute__((ext_vector_type(4))) float f32x4;
typedef __attribute__((ext_vector_type(8))) __bf16 bf16x8;
typedef __attribute__((ext_vector_type(4))) unsigned short u16x4;
typedef __attribute__((ext_vector_type(8))) unsigned short u16x8;

#define NB 4096      // batch
#define ND 512       // input dim
#define NH 2048      // mlp hidden
#define NO 512       // output dim

// ---------- helpers ----------
__device__ __forceinline__ unsigned short f2bf(float f) {
  unsigned int u = __float_as_uint(f);
  u += 0x7fffu + ((u >> 16) & 1u);          // RNE
  return (unsigned short)(u >> 16);
}
__device__ __forceinline__ float bf2f(unsigned short u) {
  return __uint_as_float(((unsigned int)u) << 16);
}
__device__ __forceinline__ void gload_lds16(const void* g, void* l) {
  __builtin_amdgcn_global_load_lds(
      (const __attribute__((address_space(1))) unsigned int*)g,
      (__attribute__((address_space(3))) unsigned int*)l, 16, 0, 0);
}

// ---------- gating ----------
__global__ void gate_kernel(const float* __restrict__ x, const float* __restrict__ emask,
                            const float* __restrict__ gw, const float* __restrict__ gb,
                            float* __restrict__ w_out, float* __restrict__ mask_out) {
  int b = blockIdx.x;
  int lane = threadIdx.x;
  float l8[8] = {0,0,0,0,0,0,0,0};
  const float* xr = x + (size_t)b * ND;
  for (int d = lane; d < ND; d += 64) {
    float xv = xr[d];
    const float* g = gw + d * 8;
#pragma unroll
    for (int e = 0; e < 8; ++e) l8[e] = fmaf(xv, g[e], l8[e]);
  }
#pragma unroll
  for (int off = 32; off > 0; off >>= 1) {
#pragma unroll
    for (int e = 0; e < 8; ++e) l8[e] += __shfl_xor(l8[e], off);
  }
  float m = -1e30f;
#pragma unroll
  for (int e = 0; e < 8; ++e) { l8[e] += gb[e]; m = fmaxf(m, l8[e]); }
  float s = 0.f, p[8];
#pragma unroll
  for (int e = 0; e < 8; ++e) { p[e] = expf(l8[e] - m); s += p[e]; }
  float inv = 1.f / s;
  float mk[8], me[8], ms = 0.f;
#pragma unroll
  for (int e = 0; e < 8; ++e) {
    mk[e] = emask[(size_t)b * 8 + e];
    me[e] = p[e] * inv * mk[e];
    ms += me[e];
  }
  float winv = 1.f / (ms + 1e-9f);
  if (lane == 0) {
#pragma unroll
    for (int e = 0; e < 8; ++e) {
      w_out[(size_t)b * 8 + e] = me[e] * winv;
      mask_out[(size_t)b * 8 + e] = mk[e];
    }
  }
}

// ---------- cast x to bf16 ----------
__global__ void cast_x_kernel(const float* __restrict__ x, unsigned short* __restrict__ xb) {
  size_t i = ((size_t)blockIdx.x * 256 + threadIdx.x) * 4;
  f32x4 v = *(const f32x4*)(x + i);
  u16x4 r;
#pragma unroll
  for (int j = 0; j < 4; ++j) r[j] = f2bf(v[j]);
  *(u16x4*)(xb + i) = r;
}

// ---------- B-spline basis ----------
__global__ void basis_kernel(const float* __restrict__ x, unsigned short* __restrict__ bas) {
  size_t t = (size_t)blockIdx.x * 256 + threadIdx.x;   // = b*512 + i
  float xv = x[t];
  const float hg = 0.4f;
  float tt[12];
#pragma unroll
  for (int j = 0; j < 12; ++j) tt[j] = -2.2f + hg * (float)j;
  float b0[11];
#pragma unroll
  for (int j = 0; j < 11; ++j) b0[j] = (tt[j] <= xv && xv < tt[j + 1]) ? 1.f : 0.f;
  float b1[10], b2[9], b3[8];
#pragma unroll
  for (int j = 0; j < 10; ++j) b1[j] = ((xv - tt[j]) * b0[j] + (tt[j + 2] - xv) * b0[j + 1]) * (1.f / (1.f * hg));
#pragma unroll
  for (int j = 0; j < 9; ++j)  b2[j] = ((xv - tt[j]) * b1[j] + (tt[j + 3] - xv) * b1[j + 1]) * (1.f / (2.f * hg));
#pragma unroll
  for (int j = 0; j < 8; ++j)  b3[j] = ((xv - tt[j]) * b2[j] + (tt[j + 4] - xv) * b2[j + 1]) * (1.f / (3.f * hg));
  u16x8 r;
#pragma unroll
  for (int j = 0; j < 8; ++j) r[j] = f2bf(b3[j]);
  *(u16x8*)(bas + t * 8) = r;
}

// ---------- transpose+cast: f32 [E][R][C] -> bf16 [E][C][R] ----------
__global__ void transpose_cast(const float* __restrict__ in, unsigned short* __restrict__ outp,
                               int R, int Cc) {
  __shared__ float tile[32][33];
  int e = blockIdx.z;
  int c0 = blockIdx.x * 32, r0 = blockIdx.y * 32;
  int tx = threadIdx.x & 31, ty = threadIdx.x >> 5;   // 32 x 8
  const float* ine = in + (size_t)e * R * Cc;
  unsigned short* oute = outp + (size_t)e * R * Cc;
#pragma unroll
  for (int j = 0; j < 32; j += 8)
    tile[ty + j][tx] = ine[(size_t)(r0 + ty + j) * Cc + (c0 + tx)];
  __syncthreads();
#pragma unroll
  for (int j = 0; j < 32; j += 8)
    oute[(size_t)(c0 + ty + j) * R + (r0 + tx)] = f2bf(tile[tx][ty + j]);
}

// ---------- ceff = coeff*scaling, repacked to [E][O][(i*8+g)] bf16 ----------
__global__ void make_cefft(const float* __restrict__ coeff, const float* __restrict__ scal,
                           unsigned short* __restrict__ outp) {
  size_t t = (size_t)blockIdx.x * 256 + threadIdx.x;  // over 4*512*512, i innermost
  int i = (int)(t & 511);
  int o = (int)((t >> 9) & 511);
  int e = (int)(t >> 18);
  size_t io = ((size_t)e * 512 + i) * 512 + o;
  const f32x4* cp = (const f32x4*)(coeff + io * 8);
  f32x4 c0 = cp[0], c1 = cp[1];
  float s = scal[io];
  u16x8 r;
#pragma unroll
  for (int j = 0; j < 4; ++j) r[j] = f2bf(c0[j] * s);
#pragma unroll
  for (int j = 0; j < 4; ++j) r[4 + j] = f2bf(c1[j] * s);
  *(u16x8*)(outp + ((size_t)e * 512 + o) * 4096 + (size_t)i * 8) = r;
}

// ---------- GEMM: C[M,N] = A[M,K] * B[N,K]^T, bf16 in/out ----------
// MODE 0: relu(acc+bias)  MODE 1: acc+bias  MODE 2: acc
// ROUND 8: same data paths as the passing R7 kernel (128x128 tile, BK=32,
// 256 threads, ring-3 LDS 48KB -> 3 WGs/CU, XOR swizzle, swapped-operand
// epilogue). Sync-only changes, from the fitted T=627cy/tile model:
//  (a) ONE barrier per K-tile. The mid-tile s_barrier+lgkmcnt(0)+
//      sched_barrier(0) are deleted: slot bi was gated by last tile's
//      vmcnt->barrier; slot pb's last readers finished before that same
//      barrier; every ds_read is consumed by a pre-barrier MFMA, so the
//      compiler's fine-grained lgkmcnt covers the read->MFMA deps and can
//      overlap ds_reads with MFMAs (~-200cy/tile).
//  (b) stage(t+2) issued at the TOP of the tile body: loads fly >=1.5 tiles
//      (>900cy HBM latency) before their vmcnt(4) -> ~-270cy/tile stall.
//      Ledger unchanged: 8 outstanding at the wait, vmcnt(4) gates tile t+1.
//  (c) setprio dropped (measured ~0/negative on lockstep GEMM, m190).
template <int MODE>
__global__ __launch_bounds__(256, 3) void gemm_bt(
    const unsigned short* __restrict__ A, size_t strideAe, int lda,
    const unsigned short* __restrict__ Bm, size_t strideBe, int ldb,
    const float* __restrict__ bias, int strideBiasE,
    unsigned short* __restrict__ C, size_t strideCe, int ldc, int K) {
  __shared__ __align__(16) char lsA[3 * 8192];
  __shared__ __align__(16) char lsB[3 * 8192];
  const int tid = threadIdx.x;
  const int lane = tid & 63, wid = tid >> 6;
  const int wr = wid >> 1, wc = wid & 1;           // 2M x 2N waves, 64x64 each
  // XCD-aware bijective swizzle (all grids here have gx*gy % 8 == 0)
  const int gx = gridDim.x;
  const int nxy = gx * gridDim.y;
  int flat = blockIdx.y * gx + blockIdx.x;
  flat = (flat & 7) * (nxy >> 3) + (flat >> 3);
  const int brow = (flat / gx) * 128, bcol = (flat % gx) * 128;
  const int e = blockIdx.z;
  const unsigned short* Ae = A + (size_t)e * strideAe;
  const unsigned short* Be = Bm + (size_t)e * strideBe;
  const int NT = K >> 5;

  const int fr = lane & 15, fc = lane >> 4;
  const int sR = tid >> 2, ssc = tid & 3;          // staging row-in-64, chunk 0-3

  auto stage = [&](int buf, int t2) {
#pragma unroll
    for (int q = 0; q < 2; ++q) {
      int R = q * 64 + sR;
      int kk = t2 * 32 + ((ssc ^ ((R >> 1) & 3)) << 3);
      gload_lds16(Ae + (size_t)(brow + R) * lda + (size_t)kk,
                  lsA + buf * 8192 + q * 4096 + tid * 16);
    }
#pragma unroll
    for (int q = 0; q < 2; ++q) {
      int R = q * 64 + sR;
      int kk = t2 * 32 + ((ssc ^ ((R >> 1) & 3)) << 3);
      gload_lds16(Be + (size_t)(bcol + R) * ldb + (size_t)kk,
                  lsB + buf * 8192 + q * 4096 + tid * 16);
    }
  };

  f32x4 acc[4][4] = {};

  // prologue: stage tiles 0,1 (8 loads); wait tile0 only (tile1 in flight)
  stage(0, 0);
  stage(1, 1);
  asm volatile("s_waitcnt vmcnt(4)" ::: "memory");
  __builtin_amdgcn_s_barrier();

  int bi = 0;
  for (int t = 0; t < NT; ++t) {
    const char* bA = lsA + bi * 8192;
    const char* bB = lsB + bi * 8192;
    const int pb = (bi == 0) ? 2 : bi - 1;       // == (t+2) % 3
    const bool pf = (t + 2 < NT);

    // issue next-next tile FIRST (max latency headroom before its vmcnt)
    if (pf) stage(pb, t + 2);

    bf16x8 af[4], bfrag[4];
#pragma unroll
    for (int i = 0; i < 4; ++i) {
      int ra = wr * 64 + i * 16 + fr;
      af[i] = *(const bf16x8*)(bA + ra * 64 + ((fc ^ ((ra >> 1) & 3)) << 4));
      int rb = wc * 64 + i * 16 + fr;
      bfrag[i] = *(const bf16x8*)(bB + rb * 64 + ((fc ^ ((rb >> 1) & 3)) << 4));
    }
#pragma unroll
    for (int mi = 0; mi < 4; ++mi)
#pragma unroll
      for (int ni = 0; ni < 4; ++ni)
        acc[mi][ni] = __builtin_amdgcn_mfma_f32_16x16x32_bf16(bfrag[ni], af[mi], acc[mi][ni], 0, 0, 0);

    if (pf)               asm volatile("s_waitcnt vmcnt(4)" ::: "memory");  // t+1 landed
    else if (t + 1 < NT)  asm volatile("s_waitcnt vmcnt(0)" ::: "memory");
    __builtin_amdgcn_s_barrier();

    bi = (bi == 2) ? 0 : bi + 1;
  }

  // ---- epilogue: swapped-operand layout -> thread holds C[row][col0..col0+3] ----
  unsigned short* Ce = C + (size_t)e * strideCe;
#pragma unroll
  for (int mi = 0; mi < 4; ++mi) {
    int row = brow + wr * 64 + mi * 16 + fr;
#pragma unroll
    for (int ni = 0; ni < 4; ++ni) {
      int col0 = bcol + wc * 64 + ni * 16 + (fc << 2);
      f32x4 bv = {0.f, 0.f, 0.f, 0.f};
      if constexpr (MODE != 2) bv = *(const f32x4*)(bias + e * strideBiasE + col0);
      u16x4 r;
#pragma unroll
      for (int j = 0; j < 4; ++j) {
        float v = acc[mi][ni][j] + bv[j];
        if constexpr (MODE == 0) v = fmaxf(v, 0.f);
        r[j] = f2bf(v);
      }
      *(u16x4*)(Ce + (size_t)row * ldc + col0) = r;
    }
  }
}

// ---------- final weighted combine ----------
__global__ void combine_kernel(const unsigned short* __restrict__ eo,
                               const float* __restrict__ w, float* __restrict__ out) {
  int b = blockIdx.x;
  int o = threadIdx.x * 4;
  float wv[8];
#pragma unroll
  for (int e = 0; e < 8; ++e) wv[e] = w[(size_t)b * 8 + e];
  f32x4 acc = {0.f, 0.f, 0.f, 0.f};
#pragma unroll
  for (int e = 0; e < 8; ++e) {
    u16x4 u = *(const u16x4*)(eo + ((size_t)e * NB + b) * NO + o);
#pragma unroll
    for (int j = 0; j < 4; ++j) acc[j] = fmaf(wv[e], bf2f(u[j]), acc[j]);
  }
  *(f32x4*)(out + (size_t)b * NO + o) = acc;
}

// ---------- launch ----------
extern "C" void kernel_launch(void* const* d_in, const int* in_sizes, int n_in,
                              void* d_out, int out_size, void* d_ws, size_t ws_size,
                              hipStream_t stream) {
  (void)in_sizes; (void)n_in; (void)out_size; (void)ws_size;
  const float* x      = (const float*)d_in[0];
  const float* emask  = (const float*)d_in[1];
  const float* gate_w = (const float*)d_in[2];
  const float* gate_b = (const float*)d_in[3];
  const float* mlp_w1 = (const float*)d_in[4];
  const float* mlp_b1 = (const float*)d_in[5];
  const float* mlp_w2 = (const float*)d_in[6];
  const float* mlp_b2 = (const float*)d_in[7];
  const float* kan_s  = (const float*)d_in[8];
  const float* kan_c  = (const float*)d_in[9];

  float* out = (float*)d_out;
  float* mask_out = out + (size_t)NB * NO;
  float* w_out    = mask_out + (size_t)NB * 8;

  char* ws = (char*)d_ws;
  size_t off = 0;
  auto take = [&](size_t bytes) { size_t r = off; off += (bytes + 255) & ~(size_t)255; return r; };
  unsigned short* w1t   = (unsigned short*)(ws + take((size_t)4 * NH * ND * 2));       // 8.39 MB
  unsigned short* w2t   = (unsigned short*)(ws + take((size_t)4 * NO * NH * 2));       // 8.39 MB
  unsigned short* cefft = (unsigned short*)(ws + take((size_t)4 * NO * (ND * 8) * 2)); // 16.78 MB
  unsigned short* xbf   = (unsigned short*)(ws + take((size_t)NB * ND * 2));           // 4.19 MB
  unsigned short* eo    = (unsigned short*)(ws + take((size_t)8 * NB * NO * 2));       // 33.55 MB
  unsigned short* hbuf  = (unsigned short*)(ws + take((size_t)4 * NB * NH * 2));       // 67.11 MB
  unsigned short* bas   = hbuf;  // basis [4096][4096] aliases hbuf (used after gemm2)
  // total 138.4 MB (proven footprint)

  gate_kernel<<<NB, 64, 0, stream>>>(x, emask, gate_w, gate_b, w_out, mask_out);
  cast_x_kernel<<<(NB * ND) / (256 * 4), 256, 0, stream>>>(x, xbf);
  transpose_cast<<<dim3(NH / 32, ND / 32, 4), 256, 0, stream>>>(mlp_w1, w1t, ND, NH);
  transpose_cast<<<dim3(NO / 32, NH / 32, 4), 256, 0, stream>>>(mlp_w2, w2t, NH, NO);
  make_cefft<<<(4 * ND * NO) / 256, 256, 0, stream>>>(kan_c, kan_s, cefft);

  // L1: h[e] = relu(x @ w1[e] + b1[e]) — 2048 WGs
  gemm_bt<0><<<dim3(NH / 128, NB / 128, 4), 256, 0, stream>>>(
      xbf, 0, ND,
      w1t, (size_t)NH * ND, ND,
      mlp_b1, NH,
      hbuf, (size_t)NB * NH, NH, ND);
  // L2: eo[e] = h[e] @ w2[e] + b2[e] — 512 WGs
  gemm_bt<1><<<dim3(NO / 128, NB / 128, 4), 256, 0, stream>>>(
      hbuf, (size_t)NB * NH, NH,
      w2t, (size_t)NO * NH, NH,
      mlp_b2, NO,
      eo, (size_t)NB * NO, NO, NH);
  // basis (aliases hbuf — safe: gemm2 has consumed hbuf)
  basis_kernel<<<(NB * ND) / 256, 256, 0, stream>>>(x, bas);
  // L3: eo[4+e] = basis @ cefft[e] — 512 WGs
  gemm_bt<2><<<dim3(NO / 128, NB / 128, 4), 256, 0, stream>>>(
      bas, 0, ND * 8,
      cefft, (size_t)NO * (ND * 8), ND * 8,
      nullptr, 0,
      eo + (size_t)4 * NB * NO, (size_t)NB * NO, NO, ND * 8);

  combine_kernel<<<NB, NO / 4, 0, stream>>>(eo, w_out, out);
}

// Round 9
// 235.012 us; speedup vs baseline: 1.1603x; 1.1603x over previous
//
#include <hip/hip_runtime.h>

// ---------- types ----------
typedef __attribute__((ext_vector_type(4))) float f32x4;
typedef __attribute__((ext_vector_type(8))) __bf16 bf16x8;
typedef __attribute__((ext_vector_type(4))) unsigned short u16x4;
typedef __attribute__((ext_vector_type(8))) unsigned short u16x8;

#define NB 4096      // batch
#define ND 512       // input dim
#define NH 2048      // mlp hidden
#define NO 512       // output dim

// ---------- helpers ----------
__device__ __forceinline__ unsigned short f2bf(float f) {
  unsigned int u = __float_as_uint(f);
  u += 0x7fffu + ((u >> 16) & 1u);          // RNE
  return (unsigned short)(u >> 16);
}
__device__ __forceinline__ float bf2f(unsigned short u) {
  return __uint_as_float(((unsigned int)u) << 16);
}
__device__ __forceinline__ void gload_lds16(const void* g, void* l) {
  __builtin_amdgcn_global_load_lds(
      (const __attribute__((address_space(1))) unsigned int*)g,
      (__attribute__((address_space(3))) unsigned int*)l, 16, 0, 0);
}

// ---------- gating ----------
__global__ void gate_kernel(const float* __restrict__ x, const float* __restrict__ emask,
                            const float* __restrict__ gw, const float* __restrict__ gb,
                            float* __restrict__ w_out, float* __restrict__ mask_out) {
  int b = blockIdx.x;
  int lane = threadIdx.x;
  float l8[8] = {0,0,0,0,0,0,0,0};
  const float* xr = x + (size_t)b * ND;
  for (int d = lane; d < ND; d += 64) {
    float xv = xr[d];
    const float* g = gw + d * 8;
#pragma unroll
    for (int e = 0; e < 8; ++e) l8[e] = fmaf(xv, g[e], l8[e]);
  }
#pragma unroll
  for (int off = 32; off > 0; off >>= 1) {
#pragma unroll
    for (int e = 0; e < 8; ++e) l8[e] += __shfl_xor(l8[e], off);
  }
  float m = -1e30f;
#pragma unroll
  for (int e = 0; e < 8; ++e) { l8[e] += gb[e]; m = fmaxf(m, l8[e]); }
  float s = 0.f, p[8];
#pragma unroll
  for (int e = 0; e < 8; ++e) { p[e] = expf(l8[e] - m); s += p[e]; }
  float inv = 1.f / s;
  float mk[8], me[8], ms = 0.f;
#pragma unroll
  for (int e = 0; e < 8; ++e) {
    mk[e] = emask[(size_t)b * 8 + e];
    me[e] = p[e] * inv * mk[e];
    ms += me[e];
  }
  float winv = 1.f / (ms + 1e-9f);
  if (lane == 0) {
#pragma unroll
    for (int e = 0; e < 8; ++e) {
      w_out[(size_t)b * 8 + e] = me[e] * winv;
      mask_out[(size_t)b * 8 + e] = mk[e];
    }
  }
}

// ---------- cast x to bf16 ----------
__global__ void cast_x_kernel(const float* __restrict__ x, unsigned short* __restrict__ xb) {
  size_t i = ((size_t)blockIdx.x * 256 + threadIdx.x) * 4;
  f32x4 v = *(const f32x4*)(x + i);
  u16x4 r;
#pragma unroll
  for (int j = 0; j < 4; ++j) r[j] = f2bf(v[j]);
  *(u16x4*)(xb + i) = r;
}

// ---------- B-spline basis ----------
__global__ void basis_kernel(const float* __restrict__ x, unsigned short* __restrict__ bas) {
  size_t t = (size_t)blockIdx.x * 256 + threadIdx.x;   // = b*512 + i
  float xv = x[t];
  const float hg = 0.4f;
  float tt[12];
#pragma unroll
  for (int j = 0; j < 12; ++j) tt[j] = -2.2f + hg * (float)j;
  float b0[11];
#pragma unroll
  for (int j = 0; j < 11; ++j) b0[j] = (tt[j] <= xv && xv < tt[j + 1]) ? 1.f : 0.f;
  float b1[10], b2[9], b3[8];
#pragma unroll
  for (int j = 0; j < 10; ++j) b1[j] = ((xv - tt[j]) * b0[j] + (tt[j + 2] - xv) * b0[j + 1]) * (1.f / (1.f * hg));
#pragma unroll
  for (int j = 0; j < 9; ++j)  b2[j] = ((xv - tt[j]) * b1[j] + (tt[j + 3] - xv) * b1[j + 1]) * (1.f / (2.f * hg));
#pragma unroll
  for (int j = 0; j < 8; ++j)  b3[j] = ((xv - tt[j]) * b2[j] + (tt[j + 4] - xv) * b2[j + 1]) * (1.f / (3.f * hg));
  u16x8 r;
#pragma unroll
  for (int j = 0; j < 8; ++j) r[j] = f2bf(b3[j]);
  *(u16x8*)(bas + t * 8) = r;
}

// ---------- transpose+cast: f32 [E][R][C] -> bf16 [E][C][R] ----------
__global__ void transpose_cast(const float* __restrict__ in, unsigned short* __restrict__ outp,
                               int R, int Cc) {
  __shared__ float tile[32][33];
  int e = blockIdx.z;
  int c0 = blockIdx.x * 32, r0 = blockIdx.y * 32;
  int tx = threadIdx.x & 31, ty = threadIdx.x >> 5;   // 32 x 8
  const float* ine = in + (size_t)e * R * Cc;
  unsigned short* oute = outp + (size_t)e * R * Cc;
#pragma unroll
  for (int j = 0; j < 32; j += 8)
    tile[ty + j][tx] = ine[(size_t)(r0 + ty + j) * Cc + (c0 + tx)];
  __syncthreads();
#pragma unroll
  for (int j = 0; j < 32; j += 8)
    oute[(size_t)(c0 + ty + j) * R + (r0 + tx)] = f2bf(tile[tx][ty + j]);
}

// ---------- ceff = coeff*scaling, repacked to [E][O][(i*8+g)] bf16 ----------
__global__ void make_cefft(const float* __restrict__ coeff, const float* __restrict__ scal,
                           unsigned short* __restrict__ outp) {
  size_t t = (size_t)blockIdx.x * 256 + threadIdx.x;  // over 4*512*512, i innermost
  int i = (int)(t & 511);
  int o = (int)((t >> 9) & 511);
  int e = (int)(t >> 18);
  size_t io = ((size_t)e * 512 + i) * 512 + o;
  const f32x4* cp = (const f32x4*)(coeff + io * 8);
  f32x4 c0 = cp[0], c1 = cp[1];
  float s = scal[io];
  u16x8 r;
#pragma unroll
  for (int j = 0; j < 4; ++j) r[j] = f2bf(c0[j] * s);
#pragma unroll
  for (int j = 0; j < 4; ++j) r[4 + j] = f2bf(c1[j] * s);
  *(u16x8*)(outp + ((size_t)e * 512 + o) * 4096 + (size_t)i * 8) = r;
}

// ---------- GEMM: C[M,N] = A[M,K] * B[N,K]^T, bf16 in/out ----------
// MODE 0: bf16 store relu(acc+bias)
// MODE 2: bf16 store raw acc (split-K partial; separate buffer per half)
// ROUND 9: R7's proven sync skeleton (ring-3, distance-2, reads->stage->
// barrier->lgkmcnt(0)->MFMA->vmcnt(4)->barrier; tile fully landed before any
// read), geometry scaled to cut chain-steps per MAC: 256x256 tile, BK=32,
// 512 threads = 8 waves (2M x 4N), per-wave 128x64 -> 32 MFMA + 12 ds_reads
// per phase (vs 16+8). LDS 3 x 32KB = 96KB. Same ledger numbers as R7
// (4 gloads/tile/thread; prologue 8 issued, vmcnt(4); steady vmcnt(4)).
// XOR swizzle (row>>1)&3 on GLOBAL source + read side (0-conflict proven).
template <int MODE>
__global__ __launch_bounds__(512, 2) void gemm_bt(
    const unsigned short* __restrict__ A, size_t strideAe, int lda,
    const unsigned short* __restrict__ Bm, size_t strideBe, int ldb,
    const float* __restrict__ bias, int strideBiasE,
    unsigned short* __restrict__ C, size_t strideCe, size_t strideHalf, int ldc,
    int Kspan, int zshift) {
  __shared__ __align__(16) char lsA[3 * 16384];
  __shared__ __align__(16) char lsB[3 * 16384];
  const int tid = threadIdx.x;
  const int lane = tid & 63, wid = tid >> 6;
  const int wr = wid >> 2, wc = wid & 3;           // 2M x 4N waves, 128x64 each
  // XCD-aware bijective swizzle (all grids here have gx*gy % 8 == 0)
  const int gx = gridDim.x;
  const int nxy = gx * gridDim.y;
  int flat = blockIdx.y * gx + blockIdx.x;
  flat = (flat & 7) * (nxy >> 3) + (flat >> 3);
  const int brow = (flat / gx) * 256, bcol = (flat % gx) * 256;
  const int z = blockIdx.z;
  const int e = z >> zshift;
  const int half = z & ((1 << zshift) - 1);
  const unsigned short* Ae = A + (size_t)e * strideAe + (size_t)half * Kspan;
  const unsigned short* Be = Bm + (size_t)e * strideBe + (size_t)half * Kspan;
  const int NT = Kspan >> 5;

  const int fr = lane & 15, fc = lane >> 4;
  const int sR = tid >> 2, ssc = tid & 3;          // staging row 0-127, chunk 0-3

  auto stage = [&](int buf, int t2) {
#pragma unroll
    for (int q = 0; q < 2; ++q) {
      int R = q * 128 + sR;
      int kk = t2 * 32 + ((ssc ^ ((R >> 1) & 3)) << 3);
      gload_lds16(Ae + (size_t)(brow + R) * lda + (size_t)kk,
                  lsA + buf * 16384 + q * 8192 + tid * 16);
    }
#pragma unroll
    for (int q = 0; q < 2; ++q) {
      int R = q * 128 + sR;
      int kk = t2 * 32 + ((ssc ^ ((R >> 1) & 3)) << 3);
      gload_lds16(Be + (size_t)(bcol + R) * ldb + (size_t)kk,
                  lsB + buf * 16384 + q * 8192 + tid * 16);
    }
  };

  f32x4 acc[8][4] = {};

  // prologue: stage tiles 0,1 (8 loads); wait tile0 only (tile1 in flight)
  stage(0, 0);
  stage(1, 1);
  asm volatile("s_waitcnt vmcnt(4)" ::: "memory");
  __builtin_amdgcn_s_barrier();

  int bi = 0;
  for (int t = 0; t < NT; ++t) {
    const char* bA = lsA + bi * 16384;
    const char* bB = lsB + bi * 16384;
    const int pb = (bi == 0) ? 2 : bi - 1;       // == (t+2) % 3
    const bool pf = (t + 2 < NT);

    bf16x8 af[8], bfrag[4];
#pragma unroll
    for (int i = 0; i < 8; ++i) {
      int ra = wr * 128 + i * 16 + fr;
      af[i] = *(const bf16x8*)(bA + ra * 64 + ((fc ^ ((ra >> 1) & 3)) << 4));
    }
#pragma unroll
    for (int n = 0; n < 4; ++n) {
      int rb = wc * 64 + n * 16 + fr;
      bfrag[n] = *(const bf16x8*)(bB + rb * 64 + ((fc ^ ((rb >> 1) & 3)) << 4));
    }
    if (pf) stage(pb, t + 2);
    __builtin_amdgcn_s_barrier();
    asm volatile("s_waitcnt lgkmcnt(0)" ::: "memory");
    __builtin_amdgcn_sched_barrier(0);
    __builtin_amdgcn_s_setprio(1);
#pragma unroll
    for (int mi = 0; mi < 8; ++mi)
#pragma unroll
      for (int ni = 0; ni < 4; ++ni)
        acc[mi][ni] = __builtin_amdgcn_mfma_f32_16x16x32_bf16(bfrag[ni], af[mi], acc[mi][ni], 0, 0, 0);
    __builtin_amdgcn_s_setprio(0);
    if (pf)               asm volatile("s_waitcnt vmcnt(4)" ::: "memory");  // t+1 landed
    else if (t + 1 < NT)  asm volatile("s_waitcnt vmcnt(0)" ::: "memory");
    __builtin_amdgcn_s_barrier();

    bi = (bi == 2) ? 0 : bi + 1;
  }

  // ---- epilogue: swapped-operand layout -> thread holds C[row][col0..col0+3] ----
  unsigned short* Ce = C + (size_t)e * strideCe + (size_t)half * strideHalf;
#pragma unroll
  for (int mi = 0; mi < 8; ++mi) {
    int row = brow + wr * 128 + mi * 16 + fr;
#pragma unroll
    for (int ni = 0; ni < 4; ++ni) {
      int col0 = bcol + wc * 64 + ni * 16 + (fc << 2);
      u16x4 r;
      if constexpr (MODE == 0) {
        f32x4 bv = *(const f32x4*)(bias + e * strideBiasE + col0);
#pragma unroll
        for (int j = 0; j < 4; ++j) r[j] = f2bf(fmaxf(acc[mi][ni][j] + bv[j], 0.f));
      } else {
#pragma unroll
        for (int j = 0; j < 4; ++j) r[j] = f2bf(acc[mi][ni][j]);
      }
      *(u16x4*)(Ce + (size_t)row * ldc + col0) = r;
    }
  }
}

// ---------- final weighted combine: sums split-K partials + bias ----------
__global__ void combine_kernel(const unsigned short* __restrict__ eoM,
                               const unsigned short* __restrict__ eoK,
                               const float* __restrict__ b2,
                               const float* __restrict__ w, float* __restrict__ out) {
  int b = blockIdx.x;
  int o = threadIdx.x * 4;
  float wv[8];
#pragma unroll
  for (int e = 0; e < 8; ++e) wv[e] = w[(size_t)b * 8 + e];
  f32x4 acc = {0.f, 0.f, 0.f, 0.f};
#pragma unroll
  for (int e = 0; e < 4; ++e) {
    u16x4 m0 = *(const u16x4*)(eoM + ((size_t)e * NB + b) * NO + o);
    u16x4 m1 = *(const u16x4*)(eoM + ((size_t)(4 + e) * NB + b) * NO + o);
    f32x4 bb = *(const f32x4*)(b2 + e * NO + o);
#pragma unroll
    for (int j = 0; j < 4; ++j)
      acc[j] = fmaf(wv[e], bf2f(m0[j]) + bf2f(m1[j]) + bb[j], acc[j]);
  }
#pragma unroll
  for (int e = 0; e < 4; ++e) {
    u16x4 k0 = *(const u16x4*)(eoK + ((size_t)e * NB + b) * NO + o);
    u16x4 k1 = *(const u16x4*)(eoK + ((size_t)(4 + e) * NB + b) * NO + o);
#pragma unroll
    for (int j = 0; j < 4; ++j)
      acc[j] = fmaf(wv[4 + e], bf2f(k0[j]) + bf2f(k1[j]), acc[j]);
  }
  *(f32x4*)(out + (size_t)b * NO + o) = acc;
}

// ---------- launch ----------
extern "C" void kernel_launch(void* const* d_in, const int* in_sizes, int n_in,
                              void* d_out, int out_size, void* d_ws, size_t ws_size,
                              hipStream_t stream) {
  (void)in_sizes; (void)n_in; (void)out_size; (void)ws_size;
  const float* x      = (const float*)d_in[0];
  const float* emask  = (const float*)d_in[1];
  const float* gate_w = (const float*)d_in[2];
  const float* gate_b = (const float*)d_in[3];
  const float* mlp_w1 = (const float*)d_in[4];
  const float* mlp_b1 = (const float*)d_in[5];
  const float* mlp_w2 = (const float*)d_in[6];
  const float* mlp_b2 = (const float*)d_in[7];
  const float* kan_s  = (const float*)d_in[8];
  const float* kan_c  = (const float*)d_in[9];

  float* out = (float*)d_out;
  float* mask_out = out + (size_t)NB * NO;
  float* w_out    = mask_out + (size_t)NB * 8;

  char* ws = (char*)d_ws;
  size_t off = 0;
  auto take = [&](size_t bytes) { size_t r = off; off += (bytes + 255) & ~(size_t)255; return r; };
  unsigned short* w1t   = (unsigned short*)(ws + take((size_t)4 * NH * ND * 2));       // 8.39 MB
  unsigned short* w2t   = (unsigned short*)(ws + take((size_t)4 * NO * NH * 2));       // 8.39 MB
  unsigned short* cefft = (unsigned short*)(ws + take((size_t)4 * NO * (ND * 8) * 2)); // 16.78 MB
  unsigned short* xbf   = (unsigned short*)(ws + take((size_t)NB * ND * 2));           // 4.19 MB
  unsigned short* eoM   = (unsigned short*)(ws + take((size_t)8 * NB * NO * 2));       // 33.55 MB [half][e]
  unsigned short* hbuf  = (unsigned short*)(ws + take((size_t)4 * NB * NH * 2));       // 67.11 MB
  unsigned short* bas   = hbuf;                                        // [4096][4096] bf16 (after L2)
  unsigned short* eoK   = (unsigned short*)((char*)hbuf + (size_t)2 * NB * NH * 2);  // [half][e], 33.55 MB
  // total 138.4 MB (proven footprint)

  gate_kernel<<<NB, 64, 0, stream>>>(x, emask, gate_w, gate_b, w_out, mask_out);
  cast_x_kernel<<<(NB * ND) / (256 * 4), 256, 0, stream>>>(x, xbf);
  transpose_cast<<<dim3(NH / 32, ND / 32, 4), 256, 0, stream>>>(mlp_w1, w1t, ND, NH);
  transpose_cast<<<dim3(NO / 32, NH / 32, 4), 256, 0, stream>>>(mlp_w2, w2t, NH, NO);
  make_cefft<<<(4 * ND * NO) / 256, 256, 0, stream>>>(kan_c, kan_s, cefft);

  // L1: h[e] = relu(x @ w1[e] + b1[e]) — 512 WGs, NT=16
  gemm_bt<0><<<dim3(NH / 256, NB / 256, 4), 512, 0, stream>>>(
      xbf, 0, ND,
      w1t, (size_t)NH * ND, ND,
      mlp_b1, NH,
      hbuf, (size_t)NB * NH, 0, NH, ND, 0);
  // L2: eoM[half][e] = h[e] @ w2[e] (raw partial) — split-K 2, 256 WGs, NT=32
  gemm_bt<2><<<dim3(NO / 256, NB / 256, 8), 512, 0, stream>>>(
      hbuf, (size_t)NB * NH, NH,
      w2t, (size_t)NO * NH, NH,
      nullptr, 0,
      eoM, (size_t)NB * NO, (size_t)4 * NB * NO, NO, NH / 2, 1);
  // basis into hbuf first half (h consumed); KAN partials go to second half
  basis_kernel<<<(NB * ND) / 256, 256, 0, stream>>>(x, bas);
  // L3: eoK[half][e] = basis @ cefft[e] (raw partial) — split-K 2, 256 WGs, NT=64
  gemm_bt<2><<<dim3(NO / 256, NB / 256, 8), 512, 0, stream>>>(
      bas, 0, ND * 8,
      cefft, (size_t)NO * (ND * 8), ND * 8,
      nullptr, 0,
      eoK, (size_t)NB * NO, (size_t)4 * NB * NO, NO, (ND * 8) / 2, 1);

  combine_kernel<<<NB, NO / 4, 0, stream>>>(eoM, eoK, mlp_b2, w_out, out);
}